// Round 1
// baseline (1753.463 us; speedup 1.0000x reference)
//
#include <hip/hip_runtime.h>

// Problem constants
#define BATCH 32
#define HIN 224
#define WIN 224
#define KCH 64
#define KS 7
#define OH 218
#define OW 218

// Tiling
#define TILE_H 112        // 16 ty * 7 rows per thread
#define TILE_W 64         // 16 tx * 4 cols per thread
#define IN_TILE_H 118     // TILE_H + 6
#define LDS_STRIDE 72     // >= 70 needed cols, multiple of 4 for b128 alignment
#define CH_PER_BLOCK 8    // channels computed per staged tile

__global__ __launch_bounds__(256, 4)
void conv7x7_kernel(const float* __restrict__ x,
                    const float* __restrict__ kern,
                    float* __restrict__ out) {
    __shared__ float tile[IN_TILE_H][LDS_STRIDE];

    const int wt = blockIdx.x;           // 0..3 (W tiles)
    const int ht = blockIdx.y;           // 0..1 (H tiles)
    const int bz = blockIdx.z;           // b * 8 + kg
    const int b  = bz >> 3;
    const int kg = bz & 7;

    const int h0 = ht * TILE_H;
    const int w0 = wt * TILE_W;

    const int tx = threadIdx.x;          // 0..15
    const int ty = threadIdx.y;          // 0..15
    const int tid = ty * 16 + tx;

    // ---- stage input tile: rows h0..h0+117, cols w0..w0+71 (zero-padded OOB) ----
    const float* xb = x + b * (HIN * WIN);
    const int NV = LDS_STRIDE / 4;       // 18 float4 per row
    for (int idx = tid; idx < IN_TILE_H * NV; idx += 256) {
        const int r  = idx / NV;
        const int cg = idx - r * NV;
        const int sr = h0 + r;
        const int sc = w0 + cg * 4;
        float4 v;
        if (sr < HIN && sc + 3 < WIN) {
            v = *reinterpret_cast<const float4*>(xb + sr * WIN + sc);
        } else {
            float t0 = (sr < HIN && sc + 0 < WIN) ? xb[sr * WIN + sc + 0] : 0.f;
            float t1 = (sr < HIN && sc + 1 < WIN) ? xb[sr * WIN + sc + 1] : 0.f;
            float t2 = (sr < HIN && sc + 2 < WIN) ? xb[sr * WIN + sc + 2] : 0.f;
            float t3 = (sr < HIN && sc + 3 < WIN) ? xb[sr * WIN + sc + 3] : 0.f;
            v = make_float4(t0, t1, t2, t3);
        }
        *reinterpret_cast<float4*>(&tile[r][cg * 4]) = v;
    }
    __syncthreads();

    const int r0 = ty * 7;   // first out-row within tile for this thread
    const int c0 = tx * 4;   // first out-col within tile

    #pragma unroll 1
    for (int kk = 0; kk < CH_PER_BLOCK; ++kk) {
        const int k = kg * CH_PER_BLOCK + kk;
        const float* __restrict__ wk = kern + k * (KS * KS);  // wave-uniform -> s_load

        float acc[7][4];
        #pragma unroll
        for (int i = 0; i < 7; ++i)
            #pragma unroll
            for (int j = 0; j < 4; ++j)
                acc[i][j] = 0.f;

        #pragma unroll
        for (int ii = 0; ii < 13; ++ii) {
            float xr[12];
            *reinterpret_cast<float4*>(&xr[0]) =
                *reinterpret_cast<const float4*>(&tile[r0 + ii][c0]);
            *reinterpret_cast<float4*>(&xr[4]) =
                *reinterpret_cast<const float4*>(&tile[r0 + ii][c0 + 4]);
            *reinterpret_cast<float4*>(&xr[8]) =
                *reinterpret_cast<const float4*>(&tile[r0 + ii][c0 + 8]);

            #pragma unroll
            for (int i = 0; i < 7; ++i) {
                const int ki = ii - i;
                if (ki >= 0 && ki < 7) {
                    #pragma unroll
                    for (int kj = 0; kj < 7; ++kj) {
                        const float wv = wk[ki * 7 + kj];
                        #pragma unroll
                        for (int j = 0; j < 4; ++j)
                            acc[i][j] = fmaf(wv, xr[kj + j], acc[i][j]);
                    }
                }
            }
        }

        // ---- store: float2 pairs (always 8B aligned; 218*4 = 872B row stride) ----
        float* ob = out + (size_t)(b * KCH + k) * (OH * OW);
        #pragma unroll
        for (int i = 0; i < 7; ++i) {
            const int orow = h0 + r0 + i;
            if (orow < OH) {
                const int ocol = w0 + c0;
                float* p = ob + orow * OW + ocol;
                if (ocol + 3 < OW) {
                    *reinterpret_cast<float2*>(p)     = make_float2(acc[i][0], acc[i][1]);
                    *reinterpret_cast<float2*>(p + 2) = make_float2(acc[i][2], acc[i][3]);
                } else {
                    #pragma unroll
                    for (int j = 0; j < 4; ++j)
                        if (ocol + j < OW) p[j] = acc[i][j];
                }
            }
        }
    }
}

extern "C" void kernel_launch(void* const* d_in, const int* in_sizes, int n_in,
                              void* d_out, int out_size, void* d_ws, size_t ws_size,
                              hipStream_t stream) {
    const float* x    = (const float*)d_in[0];   // (32,224,224) f32
    const float* kern = (const float*)d_in[1];   // (64,7,7) f32
    float* out        = (float*)d_out;           // (32,64,218,218) f32

    dim3 grid(4, 2, BATCH * (KCH / CH_PER_BLOCK));  // 4 x 2 x 256
    dim3 block(16, 16, 1);
    conv7x7_kernel<<<grid, block, 0, stream>>>(x, kern, out);
}